// Round 2
// baseline (4578.827 us; speedup 1.0000x reference)
//
#include <hip/hip_runtime.h>

// Graph scattering transform: 16x SpMM (CSR, atomic-free) + wavelet diffs.
// N=100000 nodes, E=3200000 edges, C=128 channels, output (N, C, 6).

#define C_CH 128
#define C2   64   // float2 elements per node row

// ---------------- CSR build ----------------

__global__ __launch_bounds__(256) void zero_int_kernel(int* __restrict__ p, int n) {
  int i = blockIdx.x * blockDim.x + threadIdx.x;
  if (i < n) p[i] = 0;
}

__global__ __launch_bounds__(256) void hist_kernel(const int* __restrict__ row,
                                                   int* __restrict__ cnt, int e) {
  int i = blockIdx.x * blockDim.x + threadIdx.x;
  if (i < e) atomicAdd(&cnt[row[i]], 1);
}

// Single-block exclusive scan over n counters -> row_ptr[0..n]
__global__ __launch_bounds__(1024) void scan_kernel(const int* __restrict__ cnt,
                                                    int* __restrict__ row_ptr, int n) {
  __shared__ int wsum[16];
  __shared__ int carry_s;
  int tid  = threadIdx.x;
  int lane = tid & 63;
  int wid  = tid >> 6;
  if (tid == 0) carry_s = 0;
  __syncthreads();
  for (int base = 0; base < n; base += 1024) {
    int i = base + tid;
    int v = (i < n) ? cnt[i] : 0;
    int s = v;  // inclusive wave scan
#pragma unroll
    for (int d = 1; d < 64; d <<= 1) {
      int t = __shfl_up(s, d);
      if (lane >= d) s += t;
    }
    if (lane == 63) wsum[wid] = s;
    __syncthreads();
    if (wid == 0 && lane < 16) {
      int ws = wsum[lane];
#pragma unroll
      for (int d = 1; d < 16; d <<= 1) {
        int t = __shfl_up(ws, d);
        if (lane >= d) ws += t;
      }
      wsum[lane] = ws;  // inclusive over wave sums
    }
    __syncthreads();
    int wave_off = (wid > 0) ? wsum[wid - 1] : 0;
    int carry = carry_s;
    if (i < n) row_ptr[i] = carry + wave_off + (s - v);  // exclusive prefix
    __syncthreads();
    if (tid == 0) carry_s = carry + wsum[15];
    __syncthreads();
  }
  if (threadIdx.x == 0) row_ptr[n] = carry_s;
}

__global__ __launch_bounds__(256) void copy_int_kernel(const int* __restrict__ src,
                                                       int* __restrict__ dst, int n) {
  int i = blockIdx.x * blockDim.x + threadIdx.x;
  if (i < n) dst[i] = src[i];
}

__global__ __launch_bounds__(256) void scatter_kernel(const int* __restrict__ row,
                                                      const int* __restrict__ col,
                                                      const float* __restrict__ vals,
                                                      int* __restrict__ cursor,
                                                      int* __restrict__ scol,
                                                      float* __restrict__ sval, int e) {
  int i = blockIdx.x * blockDim.x + threadIdx.x;
  if (i < e) {
    int p = atomicAdd(&cursor[row[i]], 1);
    scol[p] = col[i];
    sval[p] = vals[i];
  }
}

// ---------------- SpMM: one wave (64 lanes) per output row ----------------
// Each lane owns 2 channels (float2). Per edge: wave-uniform (col,val) load,
// coalesced 512B x-row gather, FMA into registers. 4-deep unroll for MLP.
// Optionally writes the diffusion power into output slice `slice` (fused
// save), and y may be null (t=16: only the slice is needed).

__global__ __launch_bounds__(256) void spmm_csr_kernel(const int* __restrict__ row_ptr,
                                                       const int* __restrict__ scol,
                                                       const float* __restrict__ sval,
                                                       const float* __restrict__ x,
                                                       float* __restrict__ y,
                                                       float* __restrict__ out,
                                                       int slice, int n) {
  int r    = (blockIdx.x * blockDim.x + threadIdx.x) >> 6;
  int lane = threadIdx.x & 63;
  if (r >= n) return;
  int beg = row_ptr[r];
  int end = row_ptr[r + 1];
  const float2* __restrict__ x2 = (const float2*)x;

  float ax0 = 0.f, ay0 = 0.f, ax1 = 0.f, ay1 = 0.f;
  float ax2 = 0.f, ay2 = 0.f, ax3 = 0.f, ay3 = 0.f;
  int e = beg;
  for (; e + 4 <= end; e += 4) {  // 4 independent gathers in flight per lane
    int   c0 = scol[e];
    int   c1 = scol[e + 1];
    int   c2 = scol[e + 2];
    int   c3 = scol[e + 3];
    float v0 = sval[e];
    float v1 = sval[e + 1];
    float v2 = sval[e + 2];
    float v3 = sval[e + 3];
    float2 a = x2[(size_t)c0 * C2 + lane];
    float2 b = x2[(size_t)c1 * C2 + lane];
    float2 c = x2[(size_t)c2 * C2 + lane];
    float2 d = x2[(size_t)c3 * C2 + lane];
    ax0 = fmaf(v0, a.x, ax0);
    ay0 = fmaf(v0, a.y, ay0);
    ax1 = fmaf(v1, b.x, ax1);
    ay1 = fmaf(v1, b.y, ay1);
    ax2 = fmaf(v2, c.x, ax2);
    ay2 = fmaf(v2, c.y, ay2);
    ax3 = fmaf(v3, d.x, ax3);
    ay3 = fmaf(v3, d.y, ay3);
  }
  for (; e < end; ++e) {
    int   c0 = scol[e];
    float v0 = sval[e];
    float2 a = x2[(size_t)c0 * C2 + lane];
    ax0 = fmaf(v0, a.x, ax0);
    ay0 = fmaf(v0, a.y, ay0);
  }
  float2 o;
  o.x = (ax0 + ax1) + (ax2 + ax3);
  o.y = (ay0 + ay1) + (ay2 + ay3);
  if (y) ((float2*)y)[(size_t)r * C2 + lane] = o;
  if (slice >= 0) {  // fused save of this diffusion power into out[:, :, slice]
    size_t i0 = (size_t)r * C_CH + 2 * lane;
    out[i0 * 6 + slice]       = o.x;
    out[(i0 + 1) * 6 + slice] = o.y;
  }
}

// ---------------- output assembly ----------------

// slices hold [?, Px, P2x, P4x, P8x, P16x]; rewrite to wavelet diffs.
__global__ __launch_bounds__(256) void finalize_kernel(const float* __restrict__ x,
                                                       float* __restrict__ out, int nc) {
  int i = blockIdx.x * blockDim.x + threadIdx.x;
  if (i < nc) {
    size_t b = (size_t)i * 6;
    float p0 = x[i];
    float p1 = out[b + 1];
    float p2 = out[b + 2];
    float p3 = out[b + 3];
    float p4 = out[b + 4];
    float p5 = out[b + 5];
    out[b + 0] = p0 - p1;
    out[b + 1] = p1 - p2;
    out[b + 2] = p2 - p3;
    out[b + 3] = p3 - p4;
    out[b + 4] = p4 - p5;
    out[b + 5] = p5;
  }
}

extern "C" void kernel_launch(void* const* d_in, const int* in_sizes, int n_in,
                              void* d_out, int out_size, void* d_ws, size_t ws_size,
                              hipStream_t stream) {
  const float* x    = (const float*)d_in[0];
  const float* vals = (const float*)d_in[1];
  const int*   row  = (const int*)d_in[2];
  const int*   col  = (const int*)d_in[3];
  float*       out  = (float*)d_out;

  const int NC = in_sizes[0];        // N*C = 12,800,000
  const int E  = in_sizes[1];        // 3,200,000
  const int N  = NC / C_CH;          // 100,000

  // workspace carve (256B aligned)
  char* ws = (char*)d_ws;
  size_t off = 0;
  auto carve = [&](size_t bytes) {
    char* p = ws + off;
    off += (bytes + 255) & ~(size_t)255;
    return p;
  };
  float* bufA    = (float*)carve((size_t)NC * 4);
  float* bufB    = (float*)carve((size_t)NC * 4);
  int*   row_ptr = (int*)carve((size_t)(N + 1) * 4);
  int*   cursor  = (int*)carve((size_t)N * 4);   // doubles as histogram
  int*   scol    = (int*)carve((size_t)E * 4);
  float* sval    = (float*)carve((size_t)E * 4);
  (void)ws_size;

  const int TB = 256;
  int gN  = (N + TB - 1) / TB;
  int gE  = (E + TB - 1) / TB;
  int gNC = (NC + TB - 1) / TB;
  int gSp = (N * 64 + TB - 1) / TB;  // one wave per row

  // CSR build (amortized over 16 SpMMs)
  zero_int_kernel<<<gN, TB, 0, stream>>>(cursor, N);
  hist_kernel<<<gE, TB, 0, stream>>>(row, cursor, E);
  scan_kernel<<<1, 1024, 0, stream>>>(cursor, row_ptr, N);
  copy_int_kernel<<<gN, TB, 0, stream>>>(row_ptr, cursor, N);
  scatter_kernel<<<gE, TB, 0, stream>>>(row, col, vals, cursor, scol, sval, E);

  // 16 diffusion steps, ping-pong; powers {1,2,4,8,16} fused into slices 1..5
  const float* cur = x;
  float* bufs[2] = {bufA, bufB};
  int pb = 0;
  int next_save = 1, slice = 1;
  for (int t = 1; t <= 16; ++t) {
    float* dst = (t == 16) ? nullptr : bufs[pb];  // t=16: only the slice is needed
    pb ^= 1;
    int s = -1;
    if (t == next_save) {
      s = slice;
      ++slice;
      next_save <<= 1;
    }
    spmm_csr_kernel<<<gSp, TB, 0, stream>>>(row_ptr, scol, sval, cur, dst, out, s, N);
    if (dst) cur = dst;
  }

  // powers -> wavelet differences (reads x for slice 0)
  finalize_kernel<<<gNC, TB, 0, stream>>>(x, out, NC);
}

// Round 4
// 4331.129 us; speedup vs baseline: 1.0572x; 1.0572x over previous
//
#include <hip/hip_runtime.h>

// Graph scattering transform: 16x SpMM (CSR, atomic-free) + wavelet diffs.
// N=100000 nodes, E=3200000 edges, C=128 channels, output (N, C, 6).
//
// R2 (resubmitted R3 after infra timeout): (a) saved powers go to contiguous
//     ws buffers (no stride-6 write amplification; fallback to strided saves
//     if ws too small); (b) SpMM = one row per 32-lane half-wave, float4/lane,
//     4-deep unroll (4KB in flight per wave, half the gather instr count).

#define C_CH 128
#define C4   32   // float4 elements per node row

// ---------------- CSR build ----------------

__global__ __launch_bounds__(256) void zero_int_kernel(int* __restrict__ p, int n) {
  int i = blockIdx.x * blockDim.x + threadIdx.x;
  if (i < n) p[i] = 0;
}

__global__ __launch_bounds__(256) void hist_kernel(const int* __restrict__ row,
                                                   int* __restrict__ cnt, int e) {
  int i = blockIdx.x * blockDim.x + threadIdx.x;
  if (i < e) atomicAdd(&cnt[row[i]], 1);
}

// Single-block exclusive scan over n counters -> row_ptr[0..n]
__global__ __launch_bounds__(1024) void scan_kernel(const int* __restrict__ cnt,
                                                    int* __restrict__ row_ptr, int n) {
  __shared__ int wsum[16];
  __shared__ int carry_s;
  int tid  = threadIdx.x;
  int lane = tid & 63;
  int wid  = tid >> 6;
  if (tid == 0) carry_s = 0;
  __syncthreads();
  for (int base = 0; base < n; base += 1024) {
    int i = base + tid;
    int v = (i < n) ? cnt[i] : 0;
    int s = v;  // inclusive wave scan
#pragma unroll
    for (int d = 1; d < 64; d <<= 1) {
      int t = __shfl_up(s, d);
      if (lane >= d) s += t;
    }
    if (lane == 63) wsum[wid] = s;
    __syncthreads();
    if (wid == 0 && lane < 16) {
      int ws = wsum[lane];
#pragma unroll
      for (int d = 1; d < 16; d <<= 1) {
        int t = __shfl_up(ws, d);
        if (lane >= d) ws += t;
      }
      wsum[lane] = ws;  // inclusive over wave sums
    }
    __syncthreads();
    int wave_off = (wid > 0) ? wsum[wid - 1] : 0;
    int carry = carry_s;
    if (i < n) row_ptr[i] = carry + wave_off + (s - v);  // exclusive prefix
    __syncthreads();
    if (tid == 0) carry_s = carry + wsum[15];
    __syncthreads();
  }
  if (threadIdx.x == 0) row_ptr[n] = carry_s;
}

__global__ __launch_bounds__(256) void copy_int_kernel(const int* __restrict__ src,
                                                       int* __restrict__ dst, int n) {
  int i = blockIdx.x * blockDim.x + threadIdx.x;
  if (i < n) dst[i] = src[i];
}

__global__ __launch_bounds__(256) void scatter_kernel(const int* __restrict__ row,
                                                      const int* __restrict__ col,
                                                      const float* __restrict__ vals,
                                                      int* __restrict__ cursor,
                                                      int* __restrict__ scol,
                                                      float* __restrict__ sval, int e) {
  int i = blockIdx.x * blockDim.x + threadIdx.x;
  if (i < e) {
    int p = atomicAdd(&cursor[row[i]], 1);
    scol[p] = col[i];
    sval[p] = vals[i];
  }
}

// ---------------- SpMM: one row per 32-lane half-wave ----------------
// Lane owns 4 channels (float4, 16B/lane). 4-deep unroll -> 8 gathers /
// 4KB in flight per wave. slice>=0 => also strided-save into out (fallback
// path only). y may be null.

__global__ __launch_bounds__(256) void spmm_csr_kernel(const int* __restrict__ row_ptr,
                                                       const int* __restrict__ scol,
                                                       const float* __restrict__ sval,
                                                       const float* __restrict__ x,
                                                       float* __restrict__ y,
                                                       float* __restrict__ out,
                                                       int slice, int n) {
  int r    = (blockIdx.x * blockDim.x + threadIdx.x) >> 5;
  int lane = threadIdx.x & 31;
  if (r >= n) return;
  int beg = row_ptr[r];
  int end = row_ptr[r + 1];
  const float4* __restrict__ x4 = (const float4*)x;

  float4 a0 = {0.f, 0.f, 0.f, 0.f};
  float4 a1 = {0.f, 0.f, 0.f, 0.f};
  float4 a2 = {0.f, 0.f, 0.f, 0.f};
  float4 a3 = {0.f, 0.f, 0.f, 0.f};
  int e = beg;
  for (; e + 4 <= end; e += 4) {  // 4 independent 512B gathers in flight
    int   c0 = scol[e];
    int   c1 = scol[e + 1];
    int   c2 = scol[e + 2];
    int   c3 = scol[e + 3];
    float v0 = sval[e];
    float v1 = sval[e + 1];
    float v2 = sval[e + 2];
    float v3 = sval[e + 3];
    float4 g0 = x4[(size_t)c0 * C4 + lane];
    float4 g1 = x4[(size_t)c1 * C4 + lane];
    float4 g2 = x4[(size_t)c2 * C4 + lane];
    float4 g3 = x4[(size_t)c3 * C4 + lane];
    a0.x = fmaf(v0, g0.x, a0.x); a0.y = fmaf(v0, g0.y, a0.y);
    a0.z = fmaf(v0, g0.z, a0.z); a0.w = fmaf(v0, g0.w, a0.w);
    a1.x = fmaf(v1, g1.x, a1.x); a1.y = fmaf(v1, g1.y, a1.y);
    a1.z = fmaf(v1, g1.z, a1.z); a1.w = fmaf(v1, g1.w, a1.w);
    a2.x = fmaf(v2, g2.x, a2.x); a2.y = fmaf(v2, g2.y, a2.y);
    a2.z = fmaf(v2, g2.z, a2.z); a2.w = fmaf(v2, g2.w, a2.w);
    a3.x = fmaf(v3, g3.x, a3.x); a3.y = fmaf(v3, g3.y, a3.y);
    a3.z = fmaf(v3, g3.z, a3.z); a3.w = fmaf(v3, g3.w, a3.w);
  }
  for (; e < end; ++e) {
    int   c0 = scol[e];
    float v0 = sval[e];
    float4 g0 = x4[(size_t)c0 * C4 + lane];
    a0.x = fmaf(v0, g0.x, a0.x); a0.y = fmaf(v0, g0.y, a0.y);
    a0.z = fmaf(v0, g0.z, a0.z); a0.w = fmaf(v0, g0.w, a0.w);
  }
  float4 o;
  o.x = (a0.x + a1.x) + (a2.x + a3.x);
  o.y = (a0.y + a1.y) + (a2.y + a3.y);
  o.z = (a0.z + a1.z) + (a2.z + a3.z);
  o.w = (a0.w + a1.w) + (a2.w + a3.w);
  if (y) ((float4*)y)[(size_t)r * C4 + lane] = o;
  if (slice >= 0) {  // fallback strided save into out[:, :, slice]
    size_t i0 = (size_t)r * C_CH + 4 * lane;
    out[(i0 + 0) * 6 + slice] = o.x;
    out[(i0 + 1) * 6 + slice] = o.y;
    out[(i0 + 2) * 6 + slice] = o.z;
    out[(i0 + 3) * 6 + slice] = o.w;
  }
}

// ---------------- output assembly ----------------

// Buffered path: read x + 5 contiguous power buffers, write dense (N,C,6).
__global__ __launch_bounds__(256) void finalize_buf_kernel(
    const float* __restrict__ x,  const float* __restrict__ p1,
    const float* __restrict__ p2, const float* __restrict__ p4,
    const float* __restrict__ p8, const float* __restrict__ p16,
    float* __restrict__ out, int nc) {
  int i = blockIdx.x * blockDim.x + threadIdx.x;
  if (i < nc) {
    float q0 = x[i], q1 = p1[i], q2 = p2[i], q3 = p4[i], q4 = p8[i], q5 = p16[i];
    size_t b = (size_t)i * 6;
    out[b + 0] = q0 - q1;
    out[b + 1] = q1 - q2;
    out[b + 2] = q2 - q3;
    out[b + 3] = q3 - q4;
    out[b + 4] = q4 - q5;
    out[b + 5] = q5;
  }
}

// Fallback path: slices hold [?, Px, P2x, P4x, P8x, P16x]; rewrite to diffs.
__global__ __launch_bounds__(256) void finalize_kernel(const float* __restrict__ x,
                                                       float* __restrict__ out, int nc) {
  int i = blockIdx.x * blockDim.x + threadIdx.x;
  if (i < nc) {
    size_t b = (size_t)i * 6;
    float p0 = x[i];
    float p1 = out[b + 1];
    float p2 = out[b + 2];
    float p3 = out[b + 3];
    float p4 = out[b + 4];
    float p5 = out[b + 5];
    out[b + 0] = p0 - p1;
    out[b + 1] = p1 - p2;
    out[b + 2] = p2 - p3;
    out[b + 3] = p3 - p4;
    out[b + 4] = p4 - p5;
    out[b + 5] = p5;
  }
}

extern "C" void kernel_launch(void* const* d_in, const int* in_sizes, int n_in,
                              void* d_out, int out_size, void* d_ws, size_t ws_size,
                              hipStream_t stream) {
  const float* x    = (const float*)d_in[0];
  const float* vals = (const float*)d_in[1];
  const int*   row  = (const int*)d_in[2];
  const int*   col  = (const int*)d_in[3];
  float*       out  = (float*)d_out;

  const int NC = in_sizes[0];        // N*C = 12,800,000
  const int E  = in_sizes[1];        // 3,200,000
  const int N  = NC / C_CH;          // 100,000

  // workspace carve (256B aligned)
  char* ws = (char*)d_ws;
  size_t off = 0;
  auto carve = [&](size_t bytes) {
    char* p = ws + off;
    off += (bytes + 255) & ~(size_t)255;
    return p;
  };
  int*   row_ptr = (int*)carve((size_t)(N + 1) * 4);
  int*   cursor  = (int*)carve((size_t)N * 4);   // doubles as histogram
  int*   scol    = (int*)carve((size_t)E * 4);
  float* sval    = (float*)carve((size_t)E * 4);

  const size_t buf_bytes = ((size_t)NC * 4 + 255) & ~(size_t)255;
  // buffered path needs 6 node buffers: tA, tB, pw1, pw2, pw4, pw8
  bool buffered = (off + 6 * buf_bytes) <= ws_size;

  const int TB = 256;
  int gN  = (N + TB - 1) / TB;
  int gE  = (E + TB - 1) / TB;
  int gNC = (NC + TB - 1) / TB;
  int gSp = (N * 32 + TB - 1) / TB;  // one half-wave per row

  // CSR build (amortized over 16 SpMMs)
  zero_int_kernel<<<gN, TB, 0, stream>>>(cursor, N);
  hist_kernel<<<gE, TB, 0, stream>>>(row, cursor, E);
  scan_kernel<<<1, 1024, 0, stream>>>(cursor, row_ptr, N);
  copy_int_kernel<<<gN, TB, 0, stream>>>(row_ptr, cursor, N);
  scatter_kernel<<<gE, TB, 0, stream>>>(row, col, vals, cursor, scol, sval, E);

  if (buffered) {
    float* tA  = (float*)carve(buf_bytes);
    float* tB  = (float*)carve(buf_bytes);
    float* pw1 = (float*)carve(buf_bytes);
    float* pw2 = (float*)carve(buf_bytes);
    float* pw4 = (float*)carve(buf_bytes);
    float* pw8 = (float*)carve(buf_bytes);
    // chain: every step writes one contiguous 51MB buffer; saved powers
    // (P^1,P^2,P^4,P^8) persist; P^16 ends in tB.
    const float* srcs[16] = {x,  pw1, pw2, tA,  pw4, tA, tB, tA,
                             pw8, tA, tB,  tA,  tB,  tA, tB, tA};
    float*       dsts[16] = {pw1, pw2, tA, pw4, tA,  tB, tA, pw8,
                             tA,  tB, tA,  tB,  tA,  tB, tA, tB};
    for (int t = 0; t < 16; ++t) {
      spmm_csr_kernel<<<gSp, TB, 0, stream>>>(row_ptr, scol, sval, srcs[t],
                                              dsts[t], out, -1, N);
    }
    finalize_buf_kernel<<<gNC, TB, 0, stream>>>(x, pw1, pw2, pw4, pw8, tB, out, NC);
  } else {
    // fallback: ping-pong + strided slice saves
    float* bufA = (float*)carve(buf_bytes);
    float* bufB = (float*)carve(buf_bytes);
    const float* cur = x;
    float* bufs[2] = {bufA, bufB};
    int pb = 0;
    int next_save = 1, slice = 1;
    for (int t = 1; t <= 16; ++t) {
      float* dst = (t == 16) ? nullptr : bufs[pb];
      pb ^= 1;
      int s = -1;
      if (t == next_save) {
        s = slice;
        ++slice;
        next_save <<= 1;
      }
      spmm_csr_kernel<<<gSp, TB, 0, stream>>>(row_ptr, scol, sval, cur, dst, out, s, N);
      if (dst) cur = dst;
    }
    finalize_kernel<<<gNC, TB, 0, stream>>>(x, out, NC);
  }
}